// Round 1
// baseline (1929.128 us; speedup 1.0000x reference)
//
#include <hip/hip_runtime.h>
#include <math.h>

typedef __bf16 bf8_t __attribute__((ext_vector_type(8)));
typedef short  s8_t  __attribute__((ext_vector_type(8)));
typedef float  f4_t  __attribute__((ext_vector_type(4)));

#define CIN  128
#define COUT 128
#define RES  256
#define WDIM 512
#define NCOL 136   // staged halo columns: w0-4 .. w0+131 (need w0-1..w0+129)

// round-to-nearest-even f32 -> bf16 bits (inputs finite, no NaN handling)
static __device__ __forceinline__ unsigned short f2bf(float f) {
    unsigned u = __float_as_uint(f);
    unsigned r = (u + 0x7fffu + ((u >> 16) & 1u)) >> 16;
    return (unsigned short)r;
}

// ---- prep 1: styles[b][i] = (w[b]·affine_w[i])/sqrt(512) + affine_b[i] ----
__global__ void k_styles(const float* __restrict__ w, const float* __restrict__ aw,
                         const float* __restrict__ ab, float* __restrict__ styles) {
    int t = blockIdx.x * 256 + threadIdx.x;      // 1024 threads: (b, i)
    int b = t >> 7, i = t & 127;
    const float4* wr = (const float4*)(w + b * WDIM);
    const float4* ar = (const float4*)(aw + i * WDIM);
    float s = 0.f;
    for (int j = 0; j < WDIM / 4; ++j) {
        float4 a = ar[j], c = wr[j];
        s += a.x * c.x + a.y * c.y + a.z * c.z + a.w * c.w;
    }
    styles[t] = s * 0.04419417382415922f + ab[i];   // 1/sqrt(512)
}

// ---- prep 2: w2[o][i] = sum_k weight^2 ; wb[(kh*3+kw)][o][i] = bf16(weight) ----
__global__ void k_wprep(const float* __restrict__ wt, float* __restrict__ w2,
                        unsigned short* __restrict__ wb) {
    int t = blockIdx.x * 256 + threadIdx.x;      // 16384 threads: (o, i)
    int o = t >> 7, i = t & 127;
    float s = 0.f;
    for (int kk = 0; kk < 9; ++kk) {
        float v = wt[(o * CIN + i) * 9 + kk];
        s += v * v;
        wb[(kk * COUT + o) * CIN + i] = f2bf(v);
    }
    w2[o * CIN + i] = s;
}

// ---- prep 3: dcoef[b][o] = 1/sqrt(sum_i w2[o][i]*styles[b][i]^2 + 1e-8) ----
__global__ void k_dcoef(const float* __restrict__ w2, const float* __restrict__ styles,
                        float* __restrict__ dcoef) {
    int t = blockIdx.x * 256 + threadIdx.x;      // 1024 threads: (b, o)
    int b = t >> 7, o = t & 127;
    float s = 0.f;
    for (int i = 0; i < CIN; ++i) {
        float st = styles[b * CIN + i];
        s += w2[o * CIN + i] * st * st;
    }
    dcoef[t] = 1.0f / sqrtf(s + 1e-8f);
}

// ---- main: 128 Cout x 128 px output tile per block, conv as 9 shifted GEMMs ----
__global__ __launch_bounds__(256) void k_conv(
    const float* __restrict__ x, const float* __restrict__ noise,
    const float* __restrict__ nstrp, const float* __restrict__ bias,
    const float* __restrict__ styles, const float* __restrict__ dcoef,
    const unsigned short* __restrict__ wb, float* __restrict__ out) {

    // LDS: x row tile, layout [cig=ci/8][col][8 ci] as 16B groups -> b128 r/w
    __shared__ s8_t xs[16 * NCOL];
    __shared__ float s_sty[CIN], s_dc[COUT], s_bias[COUT];

    int blk = blockIdx.x;                 // 8 * 256 * 2 = 4096
    int b   = blk >> 9;
    int rem = blk & 511;
    int h0  = rem >> 1;
    int w0  = (rem & 1) << 7;

    int tid = threadIdx.x;
    if (tid < 128) {
        s_sty[tid] = styles[b * CIN + tid];
    } else {
        s_dc[tid - 128]   = dcoef[b * COUT + tid - 128];
        s_bias[tid - 128] = bias[tid - 128];
    }

    int lane = tid & 63, wave = tid >> 6;
    int mbase = (wave & 1) * 64;          // co block of this wave
    int nbase = (wave >> 1) * 64;         // px block of this wave
    int l15 = lane & 15, quad = lane >> 4;

    f4_t acc[4][4];
    for (int m = 0; m < 4; ++m)
        for (int n = 0; n < 4; ++n)
            acc[m][n] = (f4_t)0.f;

    for (int kh = 0; kh < 3; ++kh) {
        int r = h0 - 1 + kh;
        bool rowok = (r >= 0) && (r < RES);
        int rc = rowok ? r : 0;
        const float* xrow = x + ((size_t)b * CIN * RES + rc) * RES;

        __syncthreads();   // xs reads from previous kh done (also covers s_* init)
        // ---- stage modulated bf16 x row: 16 cigroups x NCOL cols ----
        for (int it = 0; it < 9; ++it) {
            int g = it * 256 + tid;
            if (g < 16 * NCOL) {
                int cig = g / NCOL, col = g - cig * NCOL;
                int wcol = w0 - 4 + col;
                bool ok = rowok && (wcol >= 0) && (wcol < RES);
                s8_t v8;
                for (int j = 0; j < 8; ++j) {
                    int ci = cig * 8 + j;
                    float v = ok ? xrow[(size_t)ci * RES * RES + wcol] * s_sty[ci] : 0.f;
                    v8[j] = (short)f2bf(v);
                }
                xs[g] = v8;
            }
        }
        __syncthreads();

        // ---- 3 kw x 4 k-steps of 32ci; 16 MFMA per step per wave ----
        for (int kw = 0; kw < 3; ++kw) {
            const unsigned short* wbk = wb + (kh * 3 + kw) * COUT * CIN;
            for (int ks = 0; ks < 4; ++ks) {
                s8_t af[4], bfg[4];
                for (int mt = 0; mt < 4; ++mt) {
                    int co = mbase + mt * 16 + l15;
                    af[mt] = *(const s8_t*)(wbk + co * CIN + ks * 32 + quad * 8);
                }
                int cig = ks * 4 + quad;
                for (int nt = 0; nt < 4; ++nt) {
                    int col = nbase + nt * 16 + l15 + kw + 3;  // px + kw - 1 - (w0-4)
                    bfg[nt] = xs[cig * NCOL + col];
                }
                for (int mt = 0; mt < 4; ++mt)
                    for (int nt = 0; nt < 4; ++nt)
                        acc[mt][nt] = __builtin_amdgcn_mfma_f32_16x16x32_bf16(
                            __builtin_bit_cast(bf8_t, af[mt]),
                            __builtin_bit_cast(bf8_t, bfg[nt]),
                            acc[mt][nt], 0, 0, 0);
            }
        }
    }

    // ---- epilogue: demod, noise, bias, lrelu, gain, clamp ----
    float nstr = nstrp[0];
    const float* nrow = noise + h0 * RES + w0;
    float nz[4];
    for (int nt = 0; nt < 4; ++nt)
        nz[nt] = nrow[nbase + nt * 16 + l15] * nstr;

    float* orow = out + (size_t)b * COUT * RES * RES + h0 * RES + w0;
    for (int mt = 0; mt < 4; ++mt) {
        for (int rg = 0; rg < 4; ++rg) {
            int co = mbase + mt * 16 + quad * 4 + rg;   // C/D: row = quad*4+reg
            float dc = s_dc[co], bi = s_bias[co];
            for (int nt = 0; nt < 4; ++nt) {
                int px = nbase + nt * 16 + l15;          // C/D: col = lane&15
                float v = acc[mt][nt][rg] * dc + nz[nt] + bi;
                v = (v >= 0.f) ? v : 0.2f * v;
                v *= 1.4142135623730951f;                // sqrt(2) gain
                v = fminf(fmaxf(v, -256.f), 256.f);
                orow[(size_t)co * RES * RES + px] = v;
            }
        }
    }
}

extern "C" void kernel_launch(void* const* d_in, const int* in_sizes, int n_in,
                              void* d_out, int out_size, void* d_ws, size_t ws_size,
                              hipStream_t stream) {
    const float* x     = (const float*)d_in[0];
    const float* w     = (const float*)d_in[1];
    const float* aw    = (const float*)d_in[2];
    const float* ab    = (const float*)d_in[3];
    const float* wt    = (const float*)d_in[4];
    const float* noise = (const float*)d_in[5];
    const float* nstr  = (const float*)d_in[6];
    const float* bias  = (const float*)d_in[7];
    // d_in[8] = noise_mode (reference adds const noise unconditionally)

    float* ws     = (float*)d_ws;
    float* styles = ws;                    // [8][128] f32
    float* dcoef  = ws + 1024;             // [8][128] f32
    float* w2     = ws + 2048;             // [128][128] f32
    unsigned short* wb = (unsigned short*)(ws + 2048 + 16384);  // [9][128][128] bf16
    float* out = (float*)d_out;

    hipLaunchKernelGGL(k_styles, dim3(4),    dim3(256), 0, stream, w, aw, ab, styles);
    hipLaunchKernelGGL(k_wprep,  dim3(64),   dim3(256), 0, stream, wt, w2, wb);
    hipLaunchKernelGGL(k_dcoef,  dim3(4),    dim3(256), 0, stream, w2, styles, dcoef);
    hipLaunchKernelGGL(k_conv,   dim3(4096), dim3(256), 0, stream,
                       x, noise, nstr, bias, styles, dcoef, wb, out);
}